// Round 8
// baseline (332.801 us; speedup 1.0000x reference)
//
#include <hip/hip_runtime.h>

#define BINS 30
#define MMT 0.75f
#define LOSS_WEIGHT 1.0f

#define RSTRIDE 31            // 30 bins + 1 pad; lane l bin b -> bank (b-l)%32, 2-way (free)
#define NTHREADS 256
#define HWORDS (NTHREADS * RSTRIDE)   // 7936 words = 31744 B
#define CNT_ONE (1u << 20)    // count in bits [20..31]; fixed-point sum in bits [0..19]
#define SUM_MASK 0xFFFFFu
#define SSCALE 256.0f
#define INV_SSCALE (1.0f / 256.0f)

// Workspace: float gS[64] @0, uint gC[64] @256, uint gDone @512 (zeroed each launch)

// Same-acquisition A/B (r7 lesson: cross-bench absolutes are contaminated by
// session/clock variance — identical code ran 99.7us in r0's acquisition and
// 137-140us in r7's, same VALU-busy-time ~30us, same conflicts to the digit).
// Dispatch A: r7's proven loop, grid-stride, first half of data.
// Dispatch B: same body, BLOCK-CONTIGUOUS access (the one untested axis: all
// prior rounds hop 4MB/iter; B walks a sequential 128KB chunk per buffer).
// Both halves feed the same global histogram; rocprof splits their durations.
__device__ __forceinline__ void ghm_elem(float x, int tt, unsigned int* __restrict__ row) {
    // g = |sigmoid(x)-t| = sigmoid(z), bce = softplus(z), z=(1-2t)x
    float z = tt ? -x : x;
    float a = __expf(-fabsf(z));               // e^{-|z|} in (0,1]
    float h = 1.0f + a;
    float r = __builtin_amdgcn_rcpf(h);        // sigmoid(|z|)
    float g = (z >= 0.0f) ? r : 1.0f - r;      // sigmoid(z)
    float sp = fmaxf(z, 0.0f) + __logf(h);     // softplus(z) >= 0
    int b = (int)(g * 30.0f);
    b = b > (BINS - 1) ? (BINS - 1) : b;
    b = b < 0 ? 0 : b;
    // fused count|fixedpoint-sum, plain LDS RMW (thread-private row)
    row[b] += (unsigned int)(sp * SSCALE + 0.5f) + CNT_ONE;
}

__global__ __launch_bounds__(256) void ghmc_pass1(
                           const float4* __restrict__ pred4,
                           const int4*   __restrict__ tgt4,
                           float*        __restrict__ gS,
                           unsigned int* __restrict__ gC,
                           unsigned int* __restrict__ gDone,
                           const float*  __restrict__ acc_sum,
                           float*        __restrict__ out,
                           int gbase, int ngroups, int contig,
                           int totalBlocks, int do_tail, int total, float tot) {
    __shared__ unsigned int sH[HWORDS];          // per-thread fused count|sum rows
    __shared__ unsigned int sPs[4 * BINS];       // per-wave partial sums (reduce)
    __shared__ unsigned int sPc[4 * BINS];       // per-wave partial counts
    __shared__ unsigned int sLast;
    const int t = threadIdx.x;

    for (int k = t; k < HWORDS; k += NTHREADS) sH[k] = 0u;
    __syncthreads();

    unsigned int* const row = &sH[t * RSTRIDE];  // thread-private: no atomics needed

    if (contig) {
        // B: block owns a contiguous chunk; wave walks it sequentially
        const int perBlock = (ngroups + gridDim.x - 1) / gridDim.x;
        const int b0  = blockIdx.x * perBlock;
        int rem = ngroups - b0;
        const int lim = (rem < perBlock) ? rem : perBlock;   // lim<=0 -> no work
        for (int i = t; i < lim; i += NTHREADS) {
            const int g = gbase + b0 + i;
            float4 p  = pred4[g];
            int4   tv = tgt4[g];
            ghm_elem(p.x, tv.x, row);
            ghm_elem(p.y, tv.y, row);
            ghm_elem(p.z, tv.z, row);
            ghm_elem(p.w, tv.w, row);
        }
    } else {
        // A: r7's grid-stride (4MB hops) — the control arm
        const int stride = gridDim.x * blockDim.x;
        for (int i = blockIdx.x * blockDim.x + t; i < ngroups; i += stride) {
            const int g = gbase + i;
            float4 p  = pred4[g];
            int4   tv = tgt4[g];
            ghm_elem(p.x, tv.x, row);
            ghm_elem(p.y, tv.y, row);
            ghm_elem(p.z, tv.z, row);
            ghm_elem(p.w, tv.w, row);
        }
    }

    // scalar tail (total % 4 != 0); 32M divisible by 4 so normally dead code
    if (do_tail && blockIdx.x == 0 && t == 0) {
        const float* predf = (const float*)pred4;
        const int*   tgtf  = (const int*)tgt4;
        for (int e = (total / 4) * 4; e < total; ++e)
            ghm_elem(predf[e], tgtf[e], row);
    }
    __syncthreads();

    // stage 1: each wave reduces its own 64 rows; lane l<30 handles bin l
    // bounds per dispatch: <=16 iters*4 = 64 adds/row -> count <= 64*64 = 4096;
    // fixed sum <= 64 * ~106K ~= 6.8M, fits u32
    {
        const int w = t >> 6;          // wave id 0..3  (4 waves of 64)
        const int l = t & 63;
        if (l < BINS) {
            unsigned int cs = 0u, ss = 0u;
            const int r0 = w * 64;     // 64 rows per wave
            #pragma unroll 8
            for (int r2 = 0; r2 < 64; ++r2) {
                unsigned int v = sH[(r0 + r2) * RSTRIDE + l];
                cs += v >> 20;
                ss += v & SUM_MASK;
            }
            sPs[w * BINS + l] = ss;
            sPc[w * BINS + l] = cs;
        }
    }
    __syncthreads();

    // stage 2: threads 0..29 combine the 4 wave-partials, one global atomic each
    if (t < BINS) {
        unsigned int cs = 0u, ss = 0u;
        #pragma unroll
        for (int w = 0; w < 4; ++w) {
            ss += sPs[w * BINS + t];
            cs += sPc[w * BINS + t];
        }
        if (cs != 0u) {
            atomicAdd(&gS[t], (float)ss * INV_SSCALE);
            atomicAdd(&gC[t], cs);
        }
        __threadfence();               // order our atomics before the ticket
    }
    __syncthreads();

    // fused finalize: the LAST block across BOTH dispatches computes the loss.
    if (t == 0) sLast = (atomicAdd(gDone, 1u) == (unsigned int)(totalBlocks - 1)) ? 1u : 0u;
    __syncthreads();
    if (sLast && t < 64) {             // wave 0, all 64 lanes active
        unsigned int c = 0u; float s = 0.0f;
        if (t < BINS) {
            c = atomicAdd(&gC[t], 0u);          // atomic reads: coherent vs other XCDs
            s = atomicAdd(&gS[t], 0.0f);
        }
        unsigned long long m = __ballot(t < BINS && c != 0u);
        float nf = fmaxf((float)__popcll(m), 1.0f);
        float term = 0.0f;
        if (t < BINS && c != 0u) {
            float na = MMT * acc_sum[t] + (1.0f - MMT) * (float)c;
            term = (tot / na / nf) * s;
        }
        // all 64 lanes execute every __shfl; sequential b=0..29 order preserved
        float loss = 0.0f;
        for (int b = 0; b < BINS; ++b) loss += __shfl(term, b);
        if (t == 0) out[0] = (loss / tot) * LOSS_WEIGHT;
    }
}

extern "C" void kernel_launch(void* const* d_in, const int* in_sizes, int n_in,
                              void* d_out, int out_size, void* d_ws, size_t ws_size,
                              hipStream_t stream) {
    const float* pred    = (const float*)d_in[0];
    const int*   target  = (const int*)d_in[1];
    const float* acc_sum = (const float*)d_in[2];

    const int total = in_sizes[0];      // N*C = 32,000,000
    const int groupsTotal = total / 4;  // 8M float4 groups
    const int gA = groupsTotal / 2;     // first half: grid-stride control
    const int gB = groupsTotal - gA;    // second half: contiguous experiment

    float*        gS    = (float*)d_ws;
    unsigned int* gC    = (unsigned int*)((char*)d_ws + 256);
    unsigned int* gDone = (unsigned int*)((char*)d_ws + 512);

    hipMemsetAsync(d_ws, 0, 768, stream);

    const int blocks = 1024;            // 4 blocks/CU (32.8KB LDS), 16 waves/CU
    const int totalBlocks = 2 * blocks; // ticket spans both dispatches

    // Dispatch A: grid-stride (control; calibrates this acquisition's speed)
    ghmc_pass1<<<blocks, NTHREADS, 0, stream>>>(
        (const float4*)pred, (const int4*)target, gS, gC, gDone, acc_sum,
        (float*)d_out, 0, gA, /*contig=*/0, totalBlocks, /*tail=*/0,
        total, (float)total);

    // Dispatch B: block-contiguous (experiment) + scalar tail
    ghmc_pass1<<<blocks, NTHREADS, 0, stream>>>(
        (const float4*)pred, (const int4*)target, gS, gC, gDone, acc_sum,
        (float*)d_out, gA, gB, /*contig=*/1, totalBlocks, /*tail=*/1,
        total, (float)total);
}